// Round 1
// baseline (1290.227 us; speedup 1.0000x reference)
//
#include <hip/hip_runtime.h>
#include <math.h>

#define SEQ 2048
#define DMODEL 512
#define NH 8
#define DHEAD 64
#define NL 4
#define DFF 2048

typedef __attribute__((ext_vector_type(8))) short short8;
typedef __attribute__((ext_vector_type(4))) float f32x4;

__device__ __forceinline__ short f2bf(float f) {
  unsigned u = __float_as_uint(f);
  u += 0x7fffu + ((u >> 16) & 1u);
  return (short)(u >> 16);
}
__device__ __forceinline__ float silu_f(float x) { return x / (1.f + __expf(-x)); }

// ---------------- transpose fp32 (rows x cols) -> bf16 (cols x rows), batched over z ----------------
__global__ __launch_bounds__(256) void k_transpose(const float* __restrict__ src, short* __restrict__ dst,
                                                   int rows, int cols) {
  __shared__ float tile[32][33];
  size_t zoff = (size_t)blockIdx.z * rows * cols;
  src += zoff; dst += zoff;
  int bx = blockIdx.x * 32, by = blockIdx.y * 32;
  int tx = threadIdx.x & 31, ty = threadIdx.x >> 5; // 32 x 8
#pragma unroll
  for (int k = 0; k < 4; ++k)
    tile[ty + k * 8][tx] = src[(size_t)(by + ty + k * 8) * cols + bx + tx];
  __syncthreads();
#pragma unroll
  for (int k = 0; k < 4; ++k)
    dst[(size_t)(bx + ty + k * 8) * rows + by + tx] = f2bf(tile[tx][ty + k * 8]);
}

// ---------------- x = x_in + pos_emb[0,:] (reference broadcasts pos_emb[:B]!) ----------------
__global__ void k_addpos(const float* __restrict__ xi, const float* __restrict__ pos, float* __restrict__ xo) {
  int i = blockIdx.x * 256 + threadIdx.x; // float4 index
  float4 a = ((const float4*)xi)[i];
  float4 p = ((const float4*)pos)[i & 127]; // (i*4) % 512 / 4
  a.x += p.x; a.y += p.y; a.z += p.z; a.w += p.w;
  ((float4*)xo)[i] = a;
}

// ---------------- rotary sin/cos tables in fp64 ----------------
__global__ void k_sincos(float* __restrict__ sn, float* __restrict__ cs) {
  int g = blockIdx.x * 256 + threadIdx.x; // 65536 total
  int s = g >> 5, p = g & 31;
  double inv = pow(10000.0, -(double)p / 32.0);
  double a = (double)s * inv;
  float sv = (float)sin(a), cv = (float)cos(a);
  sn[s * DHEAD + 2 * p] = sv; sn[s * DHEAD + 2 * p + 1] = sv;
  cs[s * DHEAD + 2 * p] = cv; cs[s * DHEAD + 2 * p + 1] = cv;
}

// ---------------- LayerNorm row(512) fp32 -> bf16, one wave per row ----------------
__global__ __launch_bounds__(256) void k_ln(const float* __restrict__ x, const float* __restrict__ w,
                                            const float* __restrict__ b, short* __restrict__ o, float eps) {
  int wid = threadIdx.x >> 6, lane = threadIdx.x & 63;
  int row = blockIdx.x * 4 + wid;
  const float* xr = x + (size_t)row * DMODEL;
  float4 v0 = *(const float4*)(xr + lane * 8);
  float4 v1 = *(const float4*)(xr + lane * 8 + 4);
  float sm = v0.x + v0.y + v0.z + v0.w + v1.x + v1.y + v1.z + v1.w;
  float sq = v0.x * v0.x + v0.y * v0.y + v0.z * v0.z + v0.w * v0.w +
             v1.x * v1.x + v1.y * v1.y + v1.z * v1.z + v1.w * v1.w;
#pragma unroll
  for (int m = 1; m < 64; m <<= 1) { sm += __shfl_xor(sm, m); sq += __shfl_xor(sq, m); }
  float mu = sm * (1.f / 512.f);
  float rstd = rsqrtf(sq * (1.f / 512.f) - mu * mu + eps);
  const float* wr = w + lane * 8; const float* br = b + lane * 8;
  float vals[8] = {v0.x, v0.y, v0.z, v0.w, v1.x, v1.y, v1.z, v1.w};
  short t[8] __attribute__((aligned(16)));
#pragma unroll
  for (int i = 0; i < 8; ++i) t[i] = f2bf((vals[i] - mu) * rstd * wr[i] + br[i]);
  *(int4*)(o + (size_t)row * DMODEL + lane * 8) = *(int4*)t;
}

// ---------------- bf16 MFMA GEMM: C(MxN) = A(MxK) @ Bt(NxK)^T + bias, epilogues ----------------
// MODE 0: store fp32   MODE 1: silu -> bf16   MODE 2: fp32 out += acc + bias (residual)
struct GB { const short* A; const short* Bt; const float* bias; void* out; };
struct GArgs { GB b[4]; int M, N, K; };

template <int MODE, int MT>
__global__ __launch_bounds__(256) void k_gemm(GArgs ga) {
  constexpr int BM = MT * 32;
  const GB g = ga.b[blockIdx.z];
  const int K = ga.K, N = ga.N;
  const int n0 = blockIdx.x * 128;
  const int m0 = blockIdx.y * BM;
  const int tid = threadIdx.x;
  const int w = tid >> 6, lane = tid & 63, l16 = lane & 15, quad = lane >> 4;
  const int wm = (w & 1) * (MT * 16);
  const int wn = (w >> 1) * 64;
  __shared__ short As[BM * 72];
  __shared__ short Bs[128 * 72];
  f32x4 zero4 = {0.f, 0.f, 0.f, 0.f};
  f32x4 acc[MT][4];
#pragma unroll
  for (int a = 0; a < MT; ++a)
#pragma unroll
    for (int b = 0; b < 4; ++b) acc[a][b] = zero4;

  for (int k0 = 0; k0 < K; k0 += 64) {
    __syncthreads();
#pragma unroll
    for (int j = 0; j < BM * 8 / 256; ++j) {
      int c = tid + j * 256;
      int r = c >> 3, kc = (c & 7) * 8;
      *(int4*)&As[r * 72 + kc] = *(const int4*)&g.A[(size_t)(m0 + r) * K + k0 + kc];
    }
#pragma unroll
    for (int j = 0; j < 4; ++j) {
      int c = tid + j * 256;
      int r = c >> 3, kc = (c & 7) * 8;
      *(int4*)&Bs[r * 72 + kc] = *(const int4*)&g.Bt[(size_t)(n0 + r) * K + k0 + kc];
    }
    __syncthreads();
#pragma unroll
    for (int kk = 0; kk < 64; kk += 32) {
      short8 af[MT], bfr[4];
#pragma unroll
      for (int a = 0; a < MT; ++a) af[a] = *(const short8*)&As[(wm + a * 16 + l16) * 72 + kk + quad * 8];
#pragma unroll
      for (int b = 0; b < 4; ++b) bfr[b] = *(const short8*)&Bs[(wn + b * 16 + l16) * 72 + kk + quad * 8];
#pragma unroll
      for (int a = 0; a < MT; ++a)
#pragma unroll
        for (int b = 0; b < 4; ++b)
          acc[a][b] = __builtin_amdgcn_mfma_f32_16x16x32_bf16(af[a], bfr[b], acc[a][b], 0, 0, 0);
    }
  }
  // epilogue: C/D layout col=lane&15, row=quad*4+reg (m89-verified)
#pragma unroll
  for (int a = 0; a < MT; ++a) {
#pragma unroll
    for (int b = 0; b < 4; ++b) {
#pragma unroll
      for (int r = 0; r < 4; ++r) {
        int row = m0 + wm + a * 16 + quad * 4 + r;
        int col = n0 + wn + b * 16 + l16;
        float val = acc[a][b][r] + g.bias[col];
        size_t idx = (size_t)row * N + col;
        if (MODE == 0) {
          ((float*)g.out)[idx] = val;
        } else if (MODE == 1) {
          ((short*)g.out)[idx] = f2bf(silu_f(val));
        } else {
          ((float*)g.out)[idx] += val;
        }
      }
    }
  }
}

// ---------------- RoPE in-place on q (with 1/8 scale) and k ----------------
__global__ __launch_bounds__(256) void k_rope(float* __restrict__ q, float* __restrict__ k,
                                              const float* __restrict__ sn, const float* __restrict__ cs) {
  int s = blockIdx.x, t = threadIdx.x;
  int hd = t >> 5, ph = t & 31;
  int d0 = hd * DHEAD + ph * 2;
  float sv = sn[s * DHEAD + ph * 2];
  float cv = cs[s * DHEAD + ph * 2];
  size_t base = (size_t)s * DMODEL + d0;
  float2 qv = *(float2*)(q + base);
  float2 kv = *(float2*)(k + base);
  float2 qo, ko;
  qo.x = (qv.x * cv - qv.y * sv) * 0.125f;
  qo.y = (qv.y * cv + qv.x * sv) * 0.125f;
  ko.x = kv.x * cv - kv.y * sv;
  ko.y = kv.y * cv + kv.x * sv;
  *(float2*)(q + base) = qo;
  *(float2*)(k + base) = ko;
}

// ---------------- retention: partial (decay-masked QK^T)V, fp32 VALU, j-parity split ----------------
__global__ __launch_bounds__(256) void k_attn(const float* __restrict__ q, const float* __restrict__ k,
                                              const float* __restrict__ v, float* __restrict__ r0,
                                              float* __restrict__ r1) {
  int x = blockIdx.x;            // 0..31
  int hd = blockIdx.y;           // head
  int jc = blockIdx.z;           // j parity
  int ib = jc ? (31 - x) : x;    // balance: co-resident (x,jc0)+(x,jc1) ~ constant work
  int t = threadIdx.x;
  int hi = t >> 4;               // 0..15
  int lo = t & 15;               // 0..15
  __shared__ float qs[64][68], ks[64][68], sT[64][66];
  __shared__ short vs[64][64];

  double stepd = (log(1.0 / 512.0) - log(1.0 / 32.0)) / 7.0;
  double gam = 1.0 - exp(log(1.0 / 32.0) + hd * stepd);
  float l2g = (float)(log(gam) * 1.4426950408889634);

  // stage q block
  for (int c = t; c < 1024; c += 256) {
    int r = c >> 4, c4 = (c & 15) << 2;
    *(float4*)&qs[r][c4] = *(const float4*)&q[(size_t)(ib * 64 + r) * DMODEL + hd * DHEAD + c4];
  }
  float racc[4][4] = {{0.f}};

  for (int jb = jc; jb <= ib; jb += 2) {
    __syncthreads();
    for (int c = t; c < 1024; c += 256) {
      int r = c >> 4, c4 = (c & 15) << 2;
      size_t gbase = (size_t)(jb * 64 + r) * DMODEL + hd * DHEAD + c4;
      *(float4*)&ks[r][c4] = *(const float4*)&k[gbase];
      float4 fv = *(const float4*)&v[gbase];
      unsigned p0 = (unsigned)(unsigned short)f2bf(fv.x) | ((unsigned)(unsigned short)f2bf(fv.y) << 16);
      unsigned p1 = (unsigned)(unsigned short)f2bf(fv.z) | ((unsigned)(unsigned short)f2bf(fv.w) << 16);
      uint2 pk; pk.x = p0; pk.y = p1;
      *(uint2*)&vs[r][c4] = pk;
    }
    __syncthreads();
    // phase 1: sim tile
    float sacc[4][4] = {{0.f}};
#pragma unroll 4
    for (int d = 0; d < 64; d += 4) {
      float4 qv[4], kv[4];
#pragma unroll
      for (int a = 0; a < 4; ++a) qv[a] = *(const float4*)&qs[hi + 16 * a][d];
#pragma unroll
      for (int b = 0; b < 4; ++b) kv[b] = *(const float4*)&ks[lo + 16 * b][d];
#pragma unroll
      for (int a = 0; a < 4; ++a)
#pragma unroll
        for (int b = 0; b < 4; ++b)
          sacc[a][b] += qv[a].x * kv[b].x + qv[a].y * kv[b].y + qv[a].z * kv[b].z + qv[a].w * kv[b].w;
    }
#pragma unroll
    for (int a = 0; a < 4; ++a)
#pragma unroll
      for (int b = 0; b < 4; ++b) {
        int ig = ib * 64 + hi + 16 * a;
        int jg = jb * 64 + lo + 16 * b;
        int df = ig - jg;
        float dec = (df < 0) ? 0.f : exp2f(l2g * (float)df);
        sT[lo + 16 * b][hi + 16 * a] = sacc[a][b] * dec;
      }
    __syncthreads();
    // phase 2: accumulate sim @ v
    for (int j = 0; j < 64; ++j) {
      uint2 vr = *(const uint2*)&vs[j][lo * 4];
      float vx = __uint_as_float((vr.x & 0xffffu) << 16);
      float vy = __uint_as_float(vr.x & 0xffff0000u);
      float vz = __uint_as_float((vr.y & 0xffffu) << 16);
      float vw = __uint_as_float(vr.y & 0xffff0000u);
#pragma unroll
      for (int a = 0; a < 4; ++a) {
        float sj = sT[j][hi + 16 * a];
        racc[a][0] += sj * vx;
        racc[a][1] += sj * vy;
        racc[a][2] += sj * vz;
        racc[a][3] += sj * vw;
      }
    }
  }
  float* rp = jc ? r1 : r0;
#pragma unroll
  for (int a = 0; a < 4; ++a) {
    int row = ib * 64 + hi + 16 * a;
    float4 o;
    o.x = racc[a][0]; o.y = racc[a][1]; o.z = racc[a][2]; o.w = racc[a][3];
    *(float4*)&rp[(size_t)row * DMODEL + hd * DHEAD + lo * 4] = o;
  }
}

// ---------------- combine partials + per-(s,h) normalize over 64 dims, eps 1e-6 ----------------
__global__ __launch_bounds__(256) void k_retnorm(const float* __restrict__ r0, const float* __restrict__ r1,
                                                 float* __restrict__ o) {
  int wid = threadIdx.x >> 6, lane = threadIdx.x & 63;
  int row = blockIdx.x * 4 + wid; // s*NH + h
  int s = row >> 3, hd = row & 7;
  size_t base = (size_t)s * DMODEL + hd * DHEAD;
  float v = r0[base + lane] + r1[base + lane];
  float sm = v, sq = v * v;
#pragma unroll
  for (int m = 1; m < 64; m <<= 1) { sm += __shfl_xor(sm, m); sq += __shfl_xor(sq, m); }
  float mu = sm * (1.f / 64.f);
  float var = sq * (1.f / 64.f) - mu * mu;
  o[base + lane] = (v - mu) * rsqrtf(var + 1e-6f);
}

// ---------------- gr = bf16( silu(g_raw) * retn ) ----------------
__global__ void k_gate(const float* __restrict__ g, const float* __restrict__ r, short* __restrict__ o) {
  int i = blockIdx.x * 256 + threadIdx.x; // float4 index
  float4 gv = ((const float4*)g)[i];
  float4 rv = ((const float4*)r)[i];
  short t0 = f2bf(silu_f(gv.x) * rv.x);
  short t1 = f2bf(silu_f(gv.y) * rv.y);
  short t2 = f2bf(silu_f(gv.z) * rv.z);
  short t3 = f2bf(silu_f(gv.w) * rv.w);
  unsigned p0 = (unsigned)(unsigned short)t0 | ((unsigned)(unsigned short)t1 << 16);
  unsigned p1 = (unsigned)(unsigned short)t2 | ((unsigned)(unsigned short)t3 << 16);
  uint2 pk; pk.x = p0; pk.y = p1;
  ((uint2*)o)[i] = pk;
}

// ---------------- out = sigmoid(x @ Wout + bout), one wave per row ----------------
__global__ __launch_bounds__(256) void k_final(const float* __restrict__ x, const float* __restrict__ w,
                                               const float* __restrict__ bo, float* __restrict__ o) {
  int wid = threadIdx.x >> 6, lane = threadIdx.x & 63;
  int row = blockIdx.x * 4 + wid;
  const float* xr = x + (size_t)row * DMODEL;
  float4 a0 = *(const float4*)(xr + lane * 8), a1 = *(const float4*)(xr + lane * 8 + 4);
  float4 w0 = *(const float4*)(w + lane * 8), w1 = *(const float4*)(w + lane * 8 + 4);
  float sm = a0.x * w0.x + a0.y * w0.y + a0.z * w0.z + a0.w * w0.w +
             a1.x * w1.x + a1.y * w1.y + a1.z * w1.z + a1.w * w1.w;
#pragma unroll
  for (int m = 1; m < 64; m <<= 1) sm += __shfl_xor(sm, m);
  if (lane == 0) o[row] = 1.f / (1.f + __expf(-(sm + bo[0])));
}

extern "C" void kernel_launch(void* const* d_in, const int* in_sizes, int n_in,
                              void* d_out, int out_size, void* d_ws, size_t ws_size,
                              hipStream_t stream) {
  const float* x_in = (const float*)d_in[0];
  const float* pos = (const float*)d_in[1];
  const float* Wq = (const float*)d_in[2];  const float* bq = (const float*)d_in[3];
  const float* Wk = (const float*)d_in[4];  const float* bk = (const float*)d_in[5];
  const float* Wv = (const float*)d_in[6];  const float* bv = (const float*)d_in[7];
  const float* Wg = (const float*)d_in[8];  const float* bg = (const float*)d_in[9];
  const float* Wo = (const float*)d_in[10]; const float* bo = (const float*)d_in[11];
  const float* ln1w = (const float*)d_in[12]; const float* ln1b = (const float*)d_in[13];
  const float* ln2w = (const float*)d_in[14]; const float* ln2b = (const float*)d_in[15];
  const float* W1 = (const float*)d_in[16]; const float* b1 = (const float*)d_in[17];
  const float* W2 = (const float*)d_in[18]; const float* b2 = (const float*)d_in[19];
  const float* Wout = (const float*)d_in[20]; const float* bout = (const float*)d_in[21];
  float* out = (float*)d_out;

  char* ws = (char*)d_ws;
  size_t off = 0;
  auto alloc = [&](size_t bytes) -> void* {
    void* p = ws + off;
    off += (bytes + 255) & ~(size_t)255;
    return p;
  };
  const size_t DD = (size_t)DMODEL * DMODEL;
  short* wqt = (short*)alloc((size_t)NL * DD * 2);
  short* wkt = (short*)alloc((size_t)NL * DD * 2);
  short* wvt = (short*)alloc((size_t)NL * DD * 2);
  short* wgt = (short*)alloc((size_t)NL * DD * 2);
  short* wot = (short*)alloc((size_t)NL * DD * 2);
  short* w1t = (short*)alloc((size_t)NL * DMODEL * DFF * 2);
  short* w2t = (short*)alloc((size_t)NL * DMODEL * DFF * 2);
  float* xb = (float*)alloc((size_t)SEQ * DMODEL * 4);
  short* ybf = (short*)alloc((size_t)SEQ * DMODEL * 2);
  float* qraw = (float*)alloc((size_t)SEQ * DMODEL * 4);
  float* kraw = (float*)alloc((size_t)SEQ * DMODEL * 4);
  float* vraw = (float*)alloc((size_t)SEQ * DMODEL * 4);
  float* graw = (float*)alloc((size_t)SEQ * DMODEL * 4);
  float* ret0 = (float*)alloc((size_t)SEQ * DMODEL * 4);
  float* ret1 = (float*)alloc((size_t)SEQ * DMODEL * 4);
  float* retn = (float*)alloc((size_t)SEQ * DMODEL * 4);
  short* grb = (short*)alloc((size_t)SEQ * DMODEL * 2);
  short* zbf = (short*)alloc((size_t)SEQ * DMODEL * 2);
  short* hbf = (short*)alloc((size_t)SEQ * DFF * 2);
  float* sint = (float*)alloc((size_t)SEQ * DHEAD * 4);
  float* cost = (float*)alloc((size_t)SEQ * DHEAD * 4);

  // weight prep (bf16 + transpose to NxK)
  k_transpose<<<dim3(DMODEL / 32, DMODEL / 32, NL), 256, 0, stream>>>(Wq, wqt, DMODEL, DMODEL);
  k_transpose<<<dim3(DMODEL / 32, DMODEL / 32, NL), 256, 0, stream>>>(Wk, wkt, DMODEL, DMODEL);
  k_transpose<<<dim3(DMODEL / 32, DMODEL / 32, NL), 256, 0, stream>>>(Wv, wvt, DMODEL, DMODEL);
  k_transpose<<<dim3(DMODEL / 32, DMODEL / 32, NL), 256, 0, stream>>>(Wg, wgt, DMODEL, DMODEL);
  k_transpose<<<dim3(DMODEL / 32, DMODEL / 32, NL), 256, 0, stream>>>(Wo, wot, DMODEL, DMODEL);
  k_transpose<<<dim3(DFF / 32, DMODEL / 32, NL), 256, 0, stream>>>(W1, w1t, DMODEL, DFF);
  k_transpose<<<dim3(DMODEL / 32, DFF / 32, NL), 256, 0, stream>>>(W2, w2t, DFF, DMODEL);
  k_addpos<<<SEQ * DMODEL / 1024, 256, 0, stream>>>(x_in, pos, xb);
  k_sincos<<<SEQ * 32 / 256, 256, 0, stream>>>(sint, cost);

  for (int l = 0; l < NL; ++l) {
    k_ln<<<SEQ / 4, 256, 0, stream>>>(xb, ln1w + l * DMODEL, ln1b + l * DMODEL, ybf, 1e-5f);
    GArgs gq{};
    gq.M = SEQ; gq.N = DMODEL; gq.K = DMODEL;
    gq.b[0] = GB{ybf, wqt + l * DD, bq + l * DMODEL, qraw};
    gq.b[1] = GB{ybf, wkt + l * DD, bk + l * DMODEL, kraw};
    gq.b[2] = GB{ybf, wvt + l * DD, bv + l * DMODEL, vraw};
    gq.b[3] = GB{ybf, wgt + l * DD, bg + l * DMODEL, graw};
    k_gemm<0, 4><<<dim3(DMODEL / 128, SEQ / 128, 4), 256, 0, stream>>>(gq);
    k_rope<<<SEQ, 256, 0, stream>>>(qraw, kraw, sint, cost);
    k_attn<<<dim3(32, NH, 2), 256, 0, stream>>>(qraw, kraw, vraw, ret0, ret1);
    k_retnorm<<<SEQ * NH / 4, 256, 0, stream>>>(ret0, ret1, retn);
    k_gate<<<SEQ * DMODEL / 1024, 256, 0, stream>>>(graw, retn, grb);
    GArgs go{};
    go.M = SEQ; go.N = DMODEL; go.K = DMODEL;
    go.b[0] = GB{grb, wot + l * DD, bo + l * DMODEL, xb};
    k_gemm<2, 2><<<dim3(DMODEL / 128, SEQ / 64, 1), 256, 0, stream>>>(go);
    k_ln<<<SEQ / 4, 256, 0, stream>>>(xb, ln2w + l * DMODEL, ln2b + l * DMODEL, zbf, 1e-5f);
    GArgs g1{};
    g1.M = SEQ; g1.N = DFF; g1.K = DMODEL;
    g1.b[0] = GB{zbf, w1t + (size_t)l * DMODEL * DFF, b1 + l * DFF, hbf};
    k_gemm<1, 4><<<dim3(DFF / 128, SEQ / 128, 1), 256, 0, stream>>>(g1);
    GArgs g2{};
    g2.M = SEQ; g2.N = DMODEL; g2.K = DFF;
    g2.b[0] = GB{hbf, w2t + (size_t)l * DMODEL * DFF, b2 + l * DMODEL, xb};
    k_gemm<2, 2><<<dim3(DMODEL / 128, SEQ / 64, 1), 256, 0, stream>>>(g2);
  }
  k_final<<<SEQ / 4, 256, 0, stream>>>(xb, Wout, bout, out);
}

// Round 2
// 896.765 us; speedup vs baseline: 1.4388x; 1.4388x over previous
//
#include <hip/hip_runtime.h>
#include <math.h>

#define SEQ 2048
#define DMODEL 512
#define NH 8
#define DHEAD 64
#define NL 4
#define DFF 2048

typedef __attribute__((ext_vector_type(8))) short short8;
typedef __attribute__((ext_vector_type(4))) float f32x4;

__device__ __forceinline__ short f2bf(float f) {
  unsigned u = __float_as_uint(f);
  u += 0x7fffu + ((u >> 16) & 1u);
  return (short)(u >> 16);
}
__device__ __forceinline__ float silu_f(float x) { return x / (1.f + __expf(-x)); }

// ---------------- transpose fp32 (rows x cols) -> bf16 (cols x rows), batched over z ----------------
__global__ __launch_bounds__(256) void k_transpose(const float* __restrict__ src, short* __restrict__ dst,
                                                   int rows, int cols) {
  __shared__ float tile[32][33];
  size_t zoff = (size_t)blockIdx.z * rows * cols;
  src += zoff; dst += zoff;
  int bx = blockIdx.x * 32, by = blockIdx.y * 32;
  int tx = threadIdx.x & 31, ty = threadIdx.x >> 5; // 32 x 8
#pragma unroll
  for (int k = 0; k < 4; ++k)
    tile[ty + k * 8][tx] = src[(size_t)(by + ty + k * 8) * cols + bx + tx];
  __syncthreads();
#pragma unroll
  for (int k = 0; k < 4; ++k)
    dst[(size_t)(bx + ty + k * 8) * rows + by + tx] = f2bf(tile[tx][ty + k * 8]);
}

// ---------------- x = x_in + pos_emb[0,:] (reference broadcasts pos_emb[:B]!) ----------------
__global__ void k_addpos(const float* __restrict__ xi, const float* __restrict__ pos, float* __restrict__ xo) {
  int i = blockIdx.x * 256 + threadIdx.x; // float4 index
  float4 a = ((const float4*)xi)[i];
  float4 p = ((const float4*)pos)[i & 127];
  a.x += p.x; a.y += p.y; a.z += p.z; a.w += p.w;
  ((float4*)xo)[i] = a;
}

// ---------------- rotary sin/cos tables in fp64 ----------------
__global__ void k_sincos(float* __restrict__ sn, float* __restrict__ cs) {
  int g = blockIdx.x * 256 + threadIdx.x; // 65536 total
  int s = g >> 5, p = g & 31;
  double inv = pow(10000.0, -(double)p / 32.0);
  double a = (double)s * inv;
  float sv = (float)sin(a), cv = (float)cos(a);
  sn[s * DHEAD + 2 * p] = sv; sn[s * DHEAD + 2 * p + 1] = sv;
  cs[s * DHEAD + 2 * p] = cv; cs[s * DHEAD + 2 * p + 1] = cv;
}

// ---------------- LayerNorm row(512) fp32 -> bf16, one wave per row ----------------
__global__ __launch_bounds__(256) void k_ln(const float* __restrict__ x, const float* __restrict__ w,
                                            const float* __restrict__ b, short* __restrict__ o, float eps) {
  int wid = threadIdx.x >> 6, lane = threadIdx.x & 63;
  int row = blockIdx.x * 4 + wid;
  const float* xr = x + (size_t)row * DMODEL;
  float4 v0 = *(const float4*)(xr + lane * 8);
  float4 v1 = *(const float4*)(xr + lane * 8 + 4);
  float sm = v0.x + v0.y + v0.z + v0.w + v1.x + v1.y + v1.z + v1.w;
  float sq = v0.x * v0.x + v0.y * v0.y + v0.z * v0.z + v0.w * v0.w +
             v1.x * v1.x + v1.y * v1.y + v1.z * v1.z + v1.w * v1.w;
#pragma unroll
  for (int m = 1; m < 64; m <<= 1) { sm += __shfl_xor(sm, m); sq += __shfl_xor(sq, m); }
  float mu = sm * (1.f / 512.f);
  float rstd = rsqrtf(sq * (1.f / 512.f) - mu * mu + eps);
  const float* wr = w + lane * 8; const float* br = b + lane * 8;
  float vals[8] = {v0.x, v0.y, v0.z, v0.w, v1.x, v1.y, v1.z, v1.w};
  short t[8] __attribute__((aligned(16)));
#pragma unroll
  for (int i = 0; i < 8; ++i) t[i] = f2bf((vals[i] - mu) * rstd * wr[i] + br[i]);
  *(int4*)(o + (size_t)row * DMODEL + lane * 8) = *(int4*)t;
}

// ---------------- bf16 MFMA GEMM: C(MxN) = A(MxK) @ Bt(NxK)^T + bias ----------------
// mode 0: store fp32   mode 1: silu -> bf16   mode 2: fp32 out += val   mode 4: bf16 store TRANSPOSED out[col*M+row]
struct GB { const short* A; const short* Bt; const float* bias; void* out; int mode; };
struct GArgs { GB b[4]; int M, N, K; };

template <int MT>
__global__ __launch_bounds__(256) void k_gemm(GArgs ga) {
  constexpr int BM = MT * 32;
  const GB g = ga.b[blockIdx.z];
  const int K = ga.K, N = ga.N, M = ga.M;
  const int n0 = blockIdx.x * 128;
  const int m0 = blockIdx.y * BM;
  const int tid = threadIdx.x;
  const int w = tid >> 6, lane = tid & 63, l16 = lane & 15, quad = lane >> 4;
  const int wm = (w & 1) * (MT * 16);
  const int wn = (w >> 1) * 64;
  __shared__ short As[BM * 72];
  __shared__ short Bs[128 * 72];
  f32x4 zero4 = {0.f, 0.f, 0.f, 0.f};
  f32x4 acc[MT][4];
#pragma unroll
  for (int a = 0; a < MT; ++a)
#pragma unroll
    for (int b = 0; b < 4; ++b) acc[a][b] = zero4;

  for (int k0 = 0; k0 < K; k0 += 64) {
    __syncthreads();
#pragma unroll
    for (int j = 0; j < BM * 8 / 256; ++j) {
      int c = tid + j * 256;
      int r = c >> 3, kc = (c & 7) * 8;
      *(int4*)&As[r * 72 + kc] = *(const int4*)&g.A[(size_t)(m0 + r) * K + k0 + kc];
    }
#pragma unroll
    for (int j = 0; j < 4; ++j) {
      int c = tid + j * 256;
      int r = c >> 3, kc = (c & 7) * 8;
      *(int4*)&Bs[r * 72 + kc] = *(const int4*)&g.Bt[(size_t)(n0 + r) * K + k0 + kc];
    }
    __syncthreads();
#pragma unroll
    for (int kk = 0; kk < 64; kk += 32) {
      short8 af[MT], bfr[4];
#pragma unroll
      for (int a = 0; a < MT; ++a) af[a] = *(const short8*)&As[(wm + a * 16 + l16) * 72 + kk + quad * 8];
#pragma unroll
      for (int b = 0; b < 4; ++b) bfr[b] = *(const short8*)&Bs[(wn + b * 16 + l16) * 72 + kk + quad * 8];
#pragma unroll
      for (int a = 0; a < MT; ++a)
#pragma unroll
        for (int b = 0; b < 4; ++b)
          acc[a][b] = __builtin_amdgcn_mfma_f32_16x16x32_bf16(af[a], bfr[b], acc[a][b], 0, 0, 0);
    }
  }
  // epilogue: C/D layout col=lane&15, row=quad*4+reg (m89-verified)
#pragma unroll
  for (int a = 0; a < MT; ++a) {
#pragma unroll
    for (int b = 0; b < 4; ++b) {
      int row0 = m0 + wm + a * 16 + quad * 4;
      int col = n0 + wn + b * 16 + l16;
      float vals[4];
#pragma unroll
      for (int r = 0; r < 4; ++r) vals[r] = acc[a][b][r] + g.bias[col];
      if (g.mode == 4) {
        short t4[4] __attribute__((aligned(8)));
#pragma unroll
        for (int r = 0; r < 4; ++r) t4[r] = f2bf(vals[r]);
        *(uint2*)&((short*)g.out)[(size_t)col * M + row0] = *(const uint2*)t4;
      } else if (g.mode == 0) {
#pragma unroll
        for (int r = 0; r < 4; ++r) ((float*)g.out)[(size_t)(row0 + r) * N + col] = vals[r];
      } else if (g.mode == 1) {
#pragma unroll
        for (int r = 0; r < 4; ++r) ((short*)g.out)[(size_t)(row0 + r) * N + col] = f2bf(silu_f(vals[r]));
      } else {
#pragma unroll
        for (int r = 0; r < 4; ++r) ((float*)g.out)[(size_t)(row0 + r) * N + col] += vals[r];
      }
    }
  }
}

// ---------------- RoPE: fp32 q,k -> bf16 qb,kb (q scaled by 1/8) ----------------
__global__ __launch_bounds__(256) void k_rope(const float* __restrict__ q, const float* __restrict__ k,
                                              const float* __restrict__ sn, const float* __restrict__ cs,
                                              short* __restrict__ qo, short* __restrict__ ko) {
  int s = blockIdx.x * 2 + (threadIdx.x >> 7);
  int idx = (threadIdx.x & 127) * 4;
  int d = idx & 63;
  size_t base = (size_t)s * DMODEL + idx;
  float4 qv = *(const float4*)(q + base);
  float4 kv = *(const float4*)(k + base);
  float4 sv = *(const float4*)(sn + s * DHEAD + d);
  float4 cv = *(const float4*)(cs + s * DHEAD + d);
  short qt[4] __attribute__((aligned(8))), kt[4] __attribute__((aligned(8)));
  qt[0] = f2bf((qv.x * cv.x - qv.y * sv.x) * 0.125f);
  qt[1] = f2bf((qv.y * cv.y + qv.x * sv.y) * 0.125f);
  qt[2] = f2bf((qv.z * cv.z - qv.w * sv.z) * 0.125f);
  qt[3] = f2bf((qv.w * cv.w + qv.z * sv.w) * 0.125f);
  kt[0] = f2bf(kv.x * cv.x - kv.y * sv.x);
  kt[1] = f2bf(kv.y * cv.y + kv.x * sv.y);
  kt[2] = f2bf(kv.z * cv.z - kv.w * sv.z);
  kt[3] = f2bf(kv.w * cv.w + kv.z * sv.w);
  *(uint2*)(qo + base) = *(const uint2*)qt;
  *(uint2*)(ko + base) = *(const uint2*)kt;
}

// ---------------- retention via MFMA: per block 64 i-rows x 1 head, j-parity split ----------------
// qb,kb: [s][h*64+d] bf16.  vtb: V TRANSPOSED [h*64+d][s] bf16.
__global__ __launch_bounds__(256) void k_attn(const short* __restrict__ qb, const short* __restrict__ kb,
                                              const short* __restrict__ vtb, float* __restrict__ r0,
                                              float* __restrict__ r1) {
  int x = blockIdx.x, hd = blockIdx.y, jc = blockIdx.z;
  int ib = jc ? (31 - x) : x; // load balance: co-resident (x,0)+(x,1) ~ constant work
  int t = threadIdx.x;
  int w = t >> 6, lane = t & 63, l16 = lane & 15, quad = lane >> 4;
  __shared__ __align__(16) short smem[4 * 64 * 72];
  short* qs = smem;               // [64][72] A for QK^T: Q[i][d]
  short* kt = smem + 4608;        // [64][72] B for QK^T: K[j][d]
  short* vt = smem + 9216;        // [64][72] A for PV:   V^T[d][j]
  short* p  = smem + 13824;       // [64][72] B for PV:   P[i][j]

  double stepd = (log(1.0 / 512.0) - log(1.0 / 32.0)) / 7.0;
  double gam = 1.0 - exp(log(1.0 / 32.0) + hd * stepd);
  float l2g = (float)(log(gam) * 1.4426950408889634);

  // stage q tile (row-major, short8)
  for (int c = t; c < 512; c += 256) {
    int r = c >> 3, d8 = (c & 7) * 8;
    *(short8*)&qs[r * 72 + d8] = *(const short8*)&qb[(size_t)(ib * 64 + r) * DMODEL + hd * DHEAD + d8];
  }
  f32x4 oacc[4]; // O^T strip: m = d in [w*16,w*16+16), n = i in [0,64)
#pragma unroll
  for (int b = 0; b < 4; ++b) oacc[b] = {0.f, 0.f, 0.f, 0.f};

  for (int jb = jc; jb <= ib; jb += 2) {
    __syncthreads();
    for (int c = t; c < 512; c += 256) {
      int r = c >> 3, d8 = (c & 7) * 8;
      *(short8*)&kt[r * 72 + d8] = *(const short8*)&kb[(size_t)(jb * 64 + r) * DMODEL + hd * DHEAD + d8];
      *(short8*)&vt[r * 72 + d8] = *(const short8*)&vtb[(size_t)(hd * DHEAD + r) * SEQ + jb * 64 + d8];
    }
    __syncthreads();
    // QK^T: wave strip m=i in [w*16,w*16+16), n=j in [0,64)
    f32x4 sacc[4];
#pragma unroll
    for (int b = 0; b < 4; ++b) sacc[b] = {0.f, 0.f, 0.f, 0.f};
#pragma unroll
    for (int kk = 0; kk < 64; kk += 32) {
      short8 af = *(const short8*)&qs[(w * 16 + l16) * 72 + kk + quad * 8];
#pragma unroll
      for (int b = 0; b < 4; ++b) {
        short8 bf_ = *(const short8*)&kt[(b * 16 + l16) * 72 + kk + quad * 8];
        sacc[b] = __builtin_amdgcn_mfma_f32_16x16x32_bf16(af, bf_, sacc[b], 0, 0, 0);
      }
    }
    // decay + mask in C layout, write P[i][j] bf16 row-major
    int dtile = (ib - jb) * 64;
#pragma unroll
    for (int b = 0; b < 4; ++b) {
#pragma unroll
      for (int r = 0; r < 4; ++r) {
        int iloc = w * 16 + quad * 4 + r;
        int jloc = b * 16 + l16;
        int df = dtile + iloc - jloc;
        float dec = (df < 0) ? 0.f : exp2f(l2g * (float)df);
        p[iloc * 72 + jloc] = f2bf(sacc[b][r] * dec);
      }
    }
    __syncthreads();
    // PV as O^T = V^T @ P^T: A = vt[d][j], B-frag = p[i][j] (k-contiguous, natural!)
#pragma unroll
    for (int kk = 0; kk < 64; kk += 32) {
      short8 af = *(const short8*)&vt[(w * 16 + l16) * 72 + kk + quad * 8];
#pragma unroll
      for (int b = 0; b < 4; ++b) {
        short8 bf_ = *(const short8*)&p[(b * 16 + l16) * 72 + kk + quad * 8];
        oacc[b] = __builtin_amdgcn_mfma_f32_16x16x32_bf16(af, bf_, oacc[b], 0, 0, 0);
      }
    }
  }
  // epilogue: O^T(C layout) -> O[i][d] via LDS, vectorized global store
  __syncthreads();
  float* obuf = (float*)smem; // [64][68] fp32 = 17408 B (fits over qs+kt)
#pragma unroll
  for (int b = 0; b < 4; ++b) {
#pragma unroll
    for (int r = 0; r < 4; ++r) {
      int d = w * 16 + quad * 4 + r;
      int i = b * 16 + l16;
      obuf[i * 68 + d] = oacc[b][r];
    }
  }
  __syncthreads();
  float* rp = jc ? r1 : r0;
  for (int c = t; c < 1024; c += 256) {
    int r = c >> 4, d4 = (c & 15) * 4;
    *(float4*)&rp[(size_t)(ib * 64 + r) * DMODEL + hd * DHEAD + d4] = *(const float4*)&obuf[r * 68 + d4];
  }
}

// ---------------- fused: combine partials + per-(s,h) normalize + silu gate -> bf16 ----------------
__global__ __launch_bounds__(256) void k_retgate(const float* __restrict__ r0, const float* __restrict__ r1,
                                                 const float* __restrict__ g, short* __restrict__ o) {
  int wid = threadIdx.x >> 6, lane = threadIdx.x & 63;
  int row = blockIdx.x * 4 + wid; // s*NH + h
  int s = row >> 3, hd = row & 7;
  size_t base = (size_t)s * DMODEL + hd * DHEAD + lane;
  float v = r0[base] + r1[base];
  float sm = v, sq = v * v;
#pragma unroll
  for (int m = 1; m < 64; m <<= 1) { sm += __shfl_xor(sm, m); sq += __shfl_xor(sq, m); }
  float mu = sm * (1.f / 64.f);
  float var = sq * (1.f / 64.f) - mu * mu;
  float rn = (v - mu) * rsqrtf(var + 1e-6f);
  o[base] = f2bf(silu_f(g[base]) * rn);
}

// ---------------- out = sigmoid(x @ Wout + bout), one wave per row ----------------
__global__ __launch_bounds__(256) void k_final(const float* __restrict__ x, const float* __restrict__ w,
                                               const float* __restrict__ bo, float* __restrict__ o) {
  int wid = threadIdx.x >> 6, lane = threadIdx.x & 63;
  int row = blockIdx.x * 4 + wid;
  const float* xr = x + (size_t)row * DMODEL;
  float4 a0 = *(const float4*)(xr + lane * 8), a1 = *(const float4*)(xr + lane * 8 + 4);
  float4 w0 = *(const float4*)(w + lane * 8), w1 = *(const float4*)(w + lane * 8 + 4);
  float sm = a0.x * w0.x + a0.y * w0.y + a0.z * w0.z + a0.w * w0.w +
             a1.x * w1.x + a1.y * w1.y + a1.z * w1.z + a1.w * w1.w;
#pragma unroll
  for (int m = 1; m < 64; m <<= 1) sm += __shfl_xor(sm, m);
  if (lane == 0) o[row] = 1.f / (1.f + __expf(-(sm + bo[0])));
}

extern "C" void kernel_launch(void* const* d_in, const int* in_sizes, int n_in,
                              void* d_out, int out_size, void* d_ws, size_t ws_size,
                              hipStream_t stream) {
  const float* x_in = (const float*)d_in[0];
  const float* pos = (const float*)d_in[1];
  const float* Wq = (const float*)d_in[2];  const float* bq = (const float*)d_in[3];
  const float* Wk = (const float*)d_in[4];  const float* bk = (const float*)d_in[5];
  const float* Wv = (const float*)d_in[6];  const float* bv = (const float*)d_in[7];
  const float* Wg = (const float*)d_in[8];  const float* bg = (const float*)d_in[9];
  const float* Wo = (const float*)d_in[10]; const float* bo = (const float*)d_in[11];
  const float* ln1w = (const float*)d_in[12]; const float* ln1b = (const float*)d_in[13];
  const float* ln2w = (const float*)d_in[14]; const float* ln2b = (const float*)d_in[15];
  const float* W1 = (const float*)d_in[16]; const float* b1 = (const float*)d_in[17];
  const float* W2 = (const float*)d_in[18]; const float* b2 = (const float*)d_in[19];
  const float* Wout = (const float*)d_in[20]; const float* bout = (const float*)d_in[21];
  float* out = (float*)d_out;

  char* ws = (char*)d_ws;
  size_t off = 0;
  auto alloc = [&](size_t bytes) -> void* {
    void* p = ws + off;
    off += (bytes + 255) & ~(size_t)255;
    return p;
  };
  const size_t DD = (size_t)DMODEL * DMODEL;
  short* wqt = (short*)alloc((size_t)NL * DD * 2);
  short* wkt = (short*)alloc((size_t)NL * DD * 2);
  short* wvt = (short*)alloc((size_t)NL * DD * 2);
  short* wgt = (short*)alloc((size_t)NL * DD * 2);
  short* wot = (short*)alloc((size_t)NL * DD * 2);
  short* w1t = (short*)alloc((size_t)NL * DMODEL * DFF * 2);
  short* w2t = (short*)alloc((size_t)NL * DMODEL * DFF * 2);
  float* xb = (float*)alloc((size_t)SEQ * DMODEL * 4);
  short* ybf = (short*)alloc((size_t)SEQ * DMODEL * 2);
  float* qraw = (float*)alloc((size_t)SEQ * DMODEL * 4);
  float* kraw = (float*)alloc((size_t)SEQ * DMODEL * 4);
  float* graw = (float*)alloc((size_t)SEQ * DMODEL * 4);
  short* qb = (short*)alloc((size_t)SEQ * DMODEL * 2);
  short* kb = (short*)alloc((size_t)SEQ * DMODEL * 2);
  short* vtb = (short*)alloc((size_t)SEQ * DMODEL * 2);
  float* ret0 = (float*)alloc((size_t)SEQ * DMODEL * 4);
  float* ret1 = (float*)alloc((size_t)SEQ * DMODEL * 4);
  short* grb = (short*)alloc((size_t)SEQ * DMODEL * 2);
  short* zbf = (short*)alloc((size_t)SEQ * DMODEL * 2);
  short* hbf = (short*)alloc((size_t)SEQ * DFF * 2);
  float* sint = (float*)alloc((size_t)SEQ * DHEAD * 4);
  float* cost = (float*)alloc((size_t)SEQ * DHEAD * 4);

  // weight prep (bf16 + transpose to NxK)
  k_transpose<<<dim3(DMODEL / 32, DMODEL / 32, NL), 256, 0, stream>>>(Wq, wqt, DMODEL, DMODEL);
  k_transpose<<<dim3(DMODEL / 32, DMODEL / 32, NL), 256, 0, stream>>>(Wk, wkt, DMODEL, DMODEL);
  k_transpose<<<dim3(DMODEL / 32, DMODEL / 32, NL), 256, 0, stream>>>(Wv, wvt, DMODEL, DMODEL);
  k_transpose<<<dim3(DMODEL / 32, DMODEL / 32, NL), 256, 0, stream>>>(Wg, wgt, DMODEL, DMODEL);
  k_transpose<<<dim3(DMODEL / 32, DMODEL / 32, NL), 256, 0, stream>>>(Wo, wot, DMODEL, DMODEL);
  k_transpose<<<dim3(DFF / 32, DMODEL / 32, NL), 256, 0, stream>>>(W1, w1t, DMODEL, DFF);
  k_transpose<<<dim3(DMODEL / 32, DFF / 32, NL), 256, 0, stream>>>(W2, w2t, DFF, DMODEL);
  k_addpos<<<SEQ * DMODEL / 1024, 256, 0, stream>>>(x_in, pos, xb);
  k_sincos<<<SEQ * 32 / 256, 256, 0, stream>>>(sint, cost);

  for (int l = 0; l < NL; ++l) {
    k_ln<<<SEQ / 4, 256, 0, stream>>>(xb, ln1w + l * DMODEL, ln1b + l * DMODEL, ybf, 1e-5f);
    GArgs gq{};
    gq.M = SEQ; gq.N = DMODEL; gq.K = DMODEL;
    gq.b[0] = GB{ybf, wqt + l * DD, bq + l * DMODEL, qraw, 0};
    gq.b[1] = GB{ybf, wkt + l * DD, bk + l * DMODEL, kraw, 0};
    gq.b[2] = GB{ybf, wvt + l * DD, bv + l * DMODEL, vtb, 4};   // V stored transposed bf16
    gq.b[3] = GB{ybf, wgt + l * DD, bg + l * DMODEL, graw, 0};
    k_gemm<4><<<dim3(DMODEL / 128, SEQ / 128, 4), 256, 0, stream>>>(gq);
    k_rope<<<SEQ / 2, 256, 0, stream>>>(qraw, kraw, sint, cost, qb, kb);
    k_attn<<<dim3(32, NH, 2), 256, 0, stream>>>(qb, kb, vtb, ret0, ret1);
    k_retgate<<<SEQ * NH / 4, 256, 0, stream>>>(ret0, ret1, graw, grb);
    GArgs go{};
    go.M = SEQ; go.N = DMODEL; go.K = DMODEL;
    go.b[0] = GB{grb, wot + l * DD, bo + l * DMODEL, xb, 2};
    k_gemm<2><<<dim3(DMODEL / 128, SEQ / 64, 1), 256, 0, stream>>>(go);
    k_ln<<<SEQ / 4, 256, 0, stream>>>(xb, ln2w + l * DMODEL, ln2b + l * DMODEL, zbf, 1e-5f);
    GArgs g1{};
    g1.M = SEQ; g1.N = DFF; g1.K = DMODEL;
    g1.b[0] = GB{zbf, w1t + (size_t)l * DMODEL * DFF, b1 + l * DFF, hbf, 1};
    k_gemm<4><<<dim3(DFF / 128, SEQ / 128, 1), 256, 0, stream>>>(g1);
    GArgs g2{};
    g2.M = SEQ; g2.N = DMODEL; g2.K = DFF;
    g2.b[0] = GB{hbf, w2t + (size_t)l * DMODEL * DFF, b2 + l * DMODEL, xb, 2};
    k_gemm<2><<<dim3(DMODEL / 128, SEQ / 64, 1), 256, 0, stream>>>(g2);
  }
  k_final<<<SEQ / 4, 256, 0, stream>>>(xb, Wout, bout, out);
}

// Round 3
// 561.117 us; speedup vs baseline: 2.2994x; 1.5982x over previous
//
#include <hip/hip_runtime.h>
#include <math.h>
#include <stdint.h>

#define SEQ 2048
#define DMODEL 512
#define NH 8
#define DHEAD 64
#define NL 4
#define DFF 2048

typedef __attribute__((ext_vector_type(8))) short short8;
typedef __attribute__((ext_vector_type(4))) float f32x4;

__device__ __forceinline__ short f2bf(float f) {
  unsigned u = __float_as_uint(f);
  u += 0x7fffu + ((u >> 16) & 1u);
  return (short)(u >> 16);
}
__device__ __forceinline__ float silu_f(float x) { return x / (1.f + __expf(-x)); }

// async global->LDS, 16B per lane; HW dest = wave-uniform base + lane*16
__device__ __forceinline__ void cp16(const void* g, void* l) {
  __builtin_amdgcn_global_load_lds(
      (const __attribute__((address_space(1))) unsigned*)(unsigned long long)(uintptr_t)g,
      (__attribute__((address_space(3))) unsigned*)(unsigned)(uintptr_t)l, 16, 0, 0);
}

// ---------------- transpose fp32 (rows x cols) -> bf16 (cols x rows), batched over z ----------------
__global__ __launch_bounds__(256) void k_transpose(const float* __restrict__ src, short* __restrict__ dst,
                                                   int rows, int cols) {
  __shared__ float tile[32][33];
  size_t zoff = (size_t)blockIdx.z * rows * cols;
  src += zoff; dst += zoff;
  int bx = blockIdx.x * 32, by = blockIdx.y * 32;
  int tx = threadIdx.x & 31, ty = threadIdx.x >> 5; // 32 x 8
#pragma unroll
  for (int k = 0; k < 4; ++k)
    tile[ty + k * 8][tx] = src[(size_t)(by + ty + k * 8) * cols + bx + tx];
  __syncthreads();
#pragma unroll
  for (int k = 0; k < 4; ++k)
    dst[(size_t)(bx + ty + k * 8) * rows + by + tx] = f2bf(tile[tx][ty + k * 8]);
}

// ---------------- x = x_in + pos_emb[0,:] (reference broadcasts pos_emb[:B]!) ----------------
__global__ void k_addpos(const float* __restrict__ xi, const float* __restrict__ pos, float* __restrict__ xo) {
  int i = blockIdx.x * 256 + threadIdx.x; // float4 index
  float4 a = ((const float4*)xi)[i];
  float4 p = ((const float4*)pos)[i & 127];
  a.x += p.x; a.y += p.y; a.z += p.z; a.w += p.w;
  ((float4*)xo)[i] = a;
}

// ---------------- rotary sin/cos tables in fp64 ----------------
__global__ void k_sincos(float* __restrict__ sn, float* __restrict__ cs) {
  int g = blockIdx.x * 256 + threadIdx.x; // 65536 total
  int s = g >> 5, p = g & 31;
  double inv = pow(10000.0, -(double)p / 32.0);
  double a = (double)s * inv;
  float sv = (float)sin(a), cv = (float)cos(a);
  sn[s * DHEAD + 2 * p] = sv; sn[s * DHEAD + 2 * p + 1] = sv;
  cs[s * DHEAD + 2 * p] = cv; cs[s * DHEAD + 2 * p + 1] = cv;
}

// ---------------- LayerNorm row(512) fp32 -> bf16, one wave per row ----------------
__global__ __launch_bounds__(256) void k_ln(const float* __restrict__ x, const float* __restrict__ w,
                                            const float* __restrict__ b, short* __restrict__ o, float eps) {
  int wid = threadIdx.x >> 6, lane = threadIdx.x & 63;
  int row = blockIdx.x * 4 + wid;
  const float* xr = x + (size_t)row * DMODEL;
  float4 v0 = *(const float4*)(xr + lane * 8);
  float4 v1 = *(const float4*)(xr + lane * 8 + 4);
  float sm = v0.x + v0.y + v0.z + v0.w + v1.x + v1.y + v1.z + v1.w;
  float sq = v0.x * v0.x + v0.y * v0.y + v0.z * v0.z + v0.w * v0.w +
             v1.x * v1.x + v1.y * v1.y + v1.z * v1.z + v1.w * v1.w;
#pragma unroll
  for (int m = 1; m < 64; m <<= 1) { sm += __shfl_xor(sm, m); sq += __shfl_xor(sq, m); }
  float mu = sm * (1.f / 512.f);
  float rstd = rsqrtf(sq * (1.f / 512.f) - mu * mu + eps);
  const float* wr = w + lane * 8; const float* br = b + lane * 8;
  float vals[8] = {v0.x, v0.y, v0.z, v0.w, v1.x, v1.y, v1.z, v1.w};
  short t[8] __attribute__((aligned(16)));
#pragma unroll
  for (int i = 0; i < 8; ++i) t[i] = f2bf((vals[i] - mu) * rstd * wr[i] + br[i]);
  *(int4*)(o + (size_t)row * DMODEL + lane * 8) = *(int4*)t;
}

// ---------------- bf16 MFMA GEMM, 64x64 tile, dbuf LDS via global_load_lds, XOR-swizzled ----------------
// mode 0: store fp32   mode 1: silu -> bf16   mode 2: fp32 out += val   mode 4: bf16 store TRANSPOSED out[col*M+row]
struct GB { const short* A; const short* Bt; const float* bias; void* out; int mode; };
struct GArgs { GB b[4]; int M, N, K; };

__global__ __launch_bounds__(256) void k_gemm(GArgs ga) {
  const GB g = ga.b[blockIdx.z];
  const int K = ga.K, N = ga.N, M = ga.M;
  const int n0 = blockIdx.x * 64;
  const int m0 = blockIdx.y * 64;
  const int tid = threadIdx.x;
  const int w = tid >> 6, lane = tid & 63, l16 = lane & 15, quad = lane >> 4;
  const int wm = (w & 1) * 32, wn = (w >> 1) * 32;
  __shared__ __align__(16) short As[2][4096]; // [64][64] unpadded, chunk^= (row&7) swizzle
  __shared__ __align__(16) short Bs[2][4096];

  const short* Ab = g.A + (size_t)m0 * K;
  const short* Bb = g.Bt + (size_t)n0 * K;
  const int rsub = lane >> 3;              // row within 8-row segment
  const int cch = (lane & 7) ^ rsub;       // swizzled global chunk this lane fetches
  const int nIter = K >> 6;

  auto stage = [&](int buf, int k0) {
#pragma unroll
    for (int c = 0; c < 2; ++c) {
      int seg = w + 4 * c;
      cp16(Ab + (size_t)(seg * 8 + rsub) * K + k0 + cch * 8, &As[buf][seg * 512]);
      cp16(Bb + (size_t)(seg * 8 + rsub) * K + k0 + cch * 8, &Bs[buf][seg * 512]);
    }
  };

  f32x4 acc[2][2];
#pragma unroll
  for (int a = 0; a < 2; ++a)
#pragma unroll
    for (int b = 0; b < 2; ++b) acc[a][b] = {0.f, 0.f, 0.f, 0.f};

  stage(0, 0);
  for (int it = 0; it < nIter; ++it) {
    __syncthreads(); // compiler drains vmcnt here -> buf[it&1] ready
    if (it + 1 < nIter) stage((it + 1) & 1, (it + 1) << 6);
    const short* as = As[it & 1];
    const short* bs = Bs[it & 1];
#pragma unroll
    for (int kki = 0; kki < 2; ++kki) {
      int ch = ((quad + 4 * kki) ^ (l16 & 7)) * 8;
      short8 af[2], bfv[2];
#pragma unroll
      for (int a = 0; a < 2; ++a) af[a] = *(const short8*)&as[(wm + a * 16 + l16) * 64 + ch];
#pragma unroll
      for (int b = 0; b < 2; ++b) bfv[b] = *(const short8*)&bs[(wn + b * 16 + l16) * 64 + ch];
#pragma unroll
      for (int a = 0; a < 2; ++a)
#pragma unroll
        for (int b = 0; b < 2; ++b)
          acc[a][b] = __builtin_amdgcn_mfma_f32_16x16x32_bf16(af[a], bfv[b], acc[a][b], 0, 0, 0);
    }
  }
  // epilogue: C/D layout col=lane&15, row=quad*4+reg (m89-verified)
#pragma unroll
  for (int a = 0; a < 2; ++a) {
#pragma unroll
    for (int b = 0; b < 2; ++b) {
      int row0 = m0 + wm + a * 16 + quad * 4;
      int col = n0 + wn + b * 16 + l16;
      float vals[4];
#pragma unroll
      for (int r = 0; r < 4; ++r) vals[r] = acc[a][b][r] + g.bias[col];
      if (g.mode == 4) {
        short t4[4] __attribute__((aligned(8)));
#pragma unroll
        for (int r = 0; r < 4; ++r) t4[r] = f2bf(vals[r]);
        *(uint2*)&((short*)g.out)[(size_t)col * M + row0] = *(const uint2*)t4;
      } else if (g.mode == 0) {
#pragma unroll
        for (int r = 0; r < 4; ++r) ((float*)g.out)[(size_t)(row0 + r) * N + col] = vals[r];
      } else if (g.mode == 1) {
#pragma unroll
        for (int r = 0; r < 4; ++r) ((short*)g.out)[(size_t)(row0 + r) * N + col] = f2bf(silu_f(vals[r]));
      } else {
#pragma unroll
        for (int r = 0; r < 4; ++r) ((float*)g.out)[(size_t)(row0 + r) * N + col] += vals[r];
      }
    }
  }
}

// ---------------- RoPE: fp32 q,k -> bf16 qb,kb (q scaled by 1/8) ----------------
__global__ __launch_bounds__(256) void k_rope(const float* __restrict__ q, const float* __restrict__ k,
                                              const float* __restrict__ sn, const float* __restrict__ cs,
                                              short* __restrict__ qo, short* __restrict__ ko) {
  int s = blockIdx.x * 2 + (threadIdx.x >> 7);
  int idx = (threadIdx.x & 127) * 4;
  int d = idx & 63;
  size_t base = (size_t)s * DMODEL + idx;
  float4 qv = *(const float4*)(q + base);
  float4 kv = *(const float4*)(k + base);
  float4 sv = *(const float4*)(sn + s * DHEAD + d);
  float4 cv = *(const float4*)(cs + s * DHEAD + d);
  short qt[4] __attribute__((aligned(8))), kt[4] __attribute__((aligned(8)));
  qt[0] = f2bf((qv.x * cv.x - qv.y * sv.x) * 0.125f);
  qt[1] = f2bf((qv.y * cv.y + qv.x * sv.y) * 0.125f);
  qt[2] = f2bf((qv.z * cv.z - qv.w * sv.z) * 0.125f);
  qt[3] = f2bf((qv.w * cv.w + qv.z * sv.w) * 0.125f);
  kt[0] = f2bf(kv.x * cv.x - kv.y * sv.x);
  kt[1] = f2bf(kv.y * cv.y + kv.x * sv.y);
  kt[2] = f2bf(kv.z * cv.z - kv.w * sv.z);
  kt[3] = f2bf(kv.w * cv.w + kv.z * sv.w);
  *(uint2*)(qo + base) = *(const uint2*)qt;
  *(uint2*)(ko + base) = *(const uint2*)kt;
}

// ---------------- retention via MFMA: per block 64 i-rows x 1 head, j-parity split ----------------
// qb,kb: [s][h*64+d] bf16.  vtb: V TRANSPOSED [h*64+d][s] bf16.
__global__ __launch_bounds__(256) void k_attn(const short* __restrict__ qb, const short* __restrict__ kb,
                                              const short* __restrict__ vtb, float* __restrict__ r0,
                                              float* __restrict__ r1) {
  int x = blockIdx.x, hd = blockIdx.y, jc = blockIdx.z;
  int ib = jc ? (31 - x) : x; // load balance: co-resident (x,0)+(x,1) ~ constant work
  int t = threadIdx.x;
  int w = t >> 6, lane = t & 63, l16 = lane & 15, quad = lane >> 4;
  __shared__ __align__(16) short smem[4 * 64 * 72];
  short* qs = smem;               // [64][72] A for QK^T: Q[i][d]
  short* kt = smem + 4608;        // [64][72] B for QK^T: K[j][d]
  short* vt = smem + 9216;        // [64][72] A for PV:   V^T[d][j]
  short* p  = smem + 13824;       // [64][72] B for PV:   P[i][j]

  double stepd = (log(1.0 / 512.0) - log(1.0 / 32.0)) / 7.0;
  double gam = 1.0 - exp(log(1.0 / 32.0) + hd * stepd);
  float l2g = (float)(log(gam) * 1.4426950408889634);

  // stage q tile (row-major, short8)
  for (int c = t; c < 512; c += 256) {
    int r = c >> 3, d8 = (c & 7) * 8;
    *(short8*)&qs[r * 72 + d8] = *(const short8*)&qb[(size_t)(ib * 64 + r) * DMODEL + hd * DHEAD + d8];
  }
  f32x4 oacc[4]; // O^T strip: m = d in [w*16,w*16+16), n = i in [0,64)
#pragma unroll
  for (int b = 0; b < 4; ++b) oacc[b] = {0.f, 0.f, 0.f, 0.f};

  for (int jb = jc; jb <= ib; jb += 2) {
    __syncthreads();
    for (int c = t; c < 512; c += 256) {
      int r = c >> 3, d8 = (c & 7) * 8;
      *(short8*)&kt[r * 72 + d8] = *(const short8*)&kb[(size_t)(jb * 64 + r) * DMODEL + hd * DHEAD + d8];
      *(short8*)&vt[r * 72 + d8] = *(const short8*)&vtb[(size_t)(hd * DHEAD + r) * SEQ + jb * 64 + d8];
    }
    __syncthreads();
    // QK^T: wave strip m=i in [w*16,w*16+16), n=j in [0,64)
    f32x4 sacc[4];
#pragma unroll
    for (int b = 0; b < 4; ++b) sacc[b] = {0.f, 0.f, 0.f, 0.f};
#pragma unroll
    for (int kk = 0; kk < 64; kk += 32) {
      short8 af = *(const short8*)&qs[(w * 16 + l16) * 72 + kk + quad * 8];
#pragma unroll
      for (int b = 0; b < 4; ++b) {
        short8 bf_ = *(const short8*)&kt[(b * 16 + l16) * 72 + kk + quad * 8];
        sacc[b] = __builtin_amdgcn_mfma_f32_16x16x32_bf16(af, bf_, sacc[b], 0, 0, 0);
      }
    }
    // decay + mask in C layout, write P[i][j] bf16 row-major
    int dtile = (ib - jb) * 64;
#pragma unroll
    for (int b = 0; b < 4; ++b) {
#pragma unroll
      for (int r = 0; r < 4; ++r) {
        int iloc = w * 16 + quad * 4 + r;
        int jloc = b * 16 + l16;
        int df = dtile + iloc - jloc;
        float dec = (df < 0) ? 0.f : exp2f(l2g * (float)df);
        p[iloc * 72 + jloc] = f2bf(sacc[b][r] * dec);
      }
    }
    __syncthreads();
    // PV as O^T = V^T @ P^T: A = vt[d][j], B-frag = p[i][j] (k-contiguous, natural!)
#pragma unroll
    for (int kk = 0; kk < 64; kk += 32) {
      short8 af = *(const short8*)&vt[(w * 16 + l16) * 72 + kk + quad * 8];
#pragma unroll
      for (int b = 0; b < 4; ++b) {
        short8 bf_ = *(const short8*)&p[(b * 16 + l16) * 72 + kk + quad * 8];
        oacc[b] = __builtin_amdgcn_mfma_f32_16x16x32_bf16(af, bf_, oacc[b], 0, 0, 0);
      }
    }
  }
  // epilogue: O^T(C layout) -> O[i][d] via LDS, vectorized global store
  __syncthreads();
  float* obuf = (float*)smem; // [64][68] fp32 = 17408 B (fits over qs+kt)
#pragma unroll
  for (int b = 0; b < 4; ++b) {
#pragma unroll
    for (int r = 0; r < 4; ++r) {
      int d = w * 16 + quad * 4 + r;
      int i = b * 16 + l16;
      obuf[i * 68 + d] = oacc[b][r];
    }
  }
  __syncthreads();
  float* rp = jc ? r1 : r0;
  for (int c = t; c < 1024; c += 256) {
    int r = c >> 4, d4 = (c & 15) * 4;
    *(float4*)&rp[(size_t)(ib * 64 + r) * DMODEL + hd * DHEAD + d4] = *(const float4*)&obuf[r * 68 + d4];
  }
}

// ---------------- fused: combine partials + per-(s,h) normalize + silu gate -> bf16 ----------------
__global__ __launch_bounds__(256) void k_retgate(const float* __restrict__ r0, const float* __restrict__ r1,
                                                 const float* __restrict__ g, short* __restrict__ o) {
  int wid = threadIdx.x >> 6, lane = threadIdx.x & 63;
  int row = blockIdx.x * 4 + wid; // s*NH + h
  int s = row >> 3, hd = row & 7;
  size_t base = (size_t)s * DMODEL + hd * DHEAD + lane;
  float v = r0[base] + r1[base];
  float sm = v, sq = v * v;
#pragma unroll
  for (int m = 1; m < 64; m <<= 1) { sm += __shfl_xor(sm, m); sq += __shfl_xor(sq, m); }
  float mu = sm * (1.f / 64.f);
  float var = sq * (1.f / 64.f) - mu * mu;
  float rn = (v - mu) * rsqrtf(var + 1e-6f);
  o[base] = f2bf(silu_f(g[base]) * rn);
}

// ---------------- out = sigmoid(x @ Wout + bout), one wave per row ----------------
__global__ __launch_bounds__(256) void k_final(const float* __restrict__ x, const float* __restrict__ w,
                                               const float* __restrict__ bo, float* __restrict__ o) {
  int wid = threadIdx.x >> 6, lane = threadIdx.x & 63;
  int row = blockIdx.x * 4 + wid;
  const float* xr = x + (size_t)row * DMODEL;
  float4 a0 = *(const float4*)(xr + lane * 8), a1 = *(const float4*)(xr + lane * 8 + 4);
  float4 w0 = *(const float4*)(w + lane * 8), w1 = *(const float4*)(w + lane * 8 + 4);
  float sm = a0.x * w0.x + a0.y * w0.y + a0.z * w0.z + a0.w * w0.w +
             a1.x * w1.x + a1.y * w1.y + a1.z * w1.z + a1.w * w1.w;
#pragma unroll
  for (int m = 1; m < 64; m <<= 1) sm += __shfl_xor(sm, m);
  if (lane == 0) o[row] = 1.f / (1.f + __expf(-(sm + bo[0])));
}

extern "C" void kernel_launch(void* const* d_in, const int* in_sizes, int n_in,
                              void* d_out, int out_size, void* d_ws, size_t ws_size,
                              hipStream_t stream) {
  const float* x_in = (const float*)d_in[0];
  const float* pos = (const float*)d_in[1];
  const float* Wq = (const float*)d_in[2];  const float* bq = (const float*)d_in[3];
  const float* Wk = (const float*)d_in[4];  const float* bk = (const float*)d_in[5];
  const float* Wv = (const float*)d_in[6];  const float* bv = (const float*)d_in[7];
  const float* Wg = (const float*)d_in[8];  const float* bg = (const float*)d_in[9];
  const float* Wo = (const float*)d_in[10]; const float* bo = (const float*)d_in[11];
  const float* ln1w = (const float*)d_in[12]; const float* ln1b = (const float*)d_in[13];
  const float* ln2w = (const float*)d_in[14]; const float* ln2b = (const float*)d_in[15];
  const float* W1 = (const float*)d_in[16]; const float* b1 = (const float*)d_in[17];
  const float* W2 = (const float*)d_in[18]; const float* b2 = (const float*)d_in[19];
  const float* Wout = (const float*)d_in[20]; const float* bout = (const float*)d_in[21];
  float* out = (float*)d_out;

  char* ws = (char*)d_ws;
  size_t off = 0;
  auto alloc = [&](size_t bytes) -> void* {
    void* p = ws + off;
    off += (bytes + 255) & ~(size_t)255;
    return p;
  };
  const size_t DD = (size_t)DMODEL * DMODEL;
  short* wqt = (short*)alloc((size_t)NL * DD * 2);
  short* wkt = (short*)alloc((size_t)NL * DD * 2);
  short* wvt = (short*)alloc((size_t)NL * DD * 2);
  short* wgt = (short*)alloc((size_t)NL * DD * 2);
  short* wot = (short*)alloc((size_t)NL * DD * 2);
  short* w1t = (short*)alloc((size_t)NL * DMODEL * DFF * 2);
  short* w2t = (short*)alloc((size_t)NL * DMODEL * DFF * 2);
  float* xb = (float*)alloc((size_t)SEQ * DMODEL * 4);
  short* ybf = (short*)alloc((size_t)SEQ * DMODEL * 2);
  float* qraw = (float*)alloc((size_t)SEQ * DMODEL * 4);
  float* kraw = (float*)alloc((size_t)SEQ * DMODEL * 4);
  float* graw = (float*)alloc((size_t)SEQ * DMODEL * 4);
  short* qb = (short*)alloc((size_t)SEQ * DMODEL * 2);
  short* kb = (short*)alloc((size_t)SEQ * DMODEL * 2);
  short* vtb = (short*)alloc((size_t)SEQ * DMODEL * 2);
  float* ret0 = (float*)alloc((size_t)SEQ * DMODEL * 4);
  float* ret1 = (float*)alloc((size_t)SEQ * DMODEL * 4);
  short* grb = (short*)alloc((size_t)SEQ * DMODEL * 2);
  short* zbf = (short*)alloc((size_t)SEQ * DMODEL * 2);
  short* hbf = (short*)alloc((size_t)SEQ * DFF * 2);
  float* sint = (float*)alloc((size_t)SEQ * DHEAD * 4);
  float* cost = (float*)alloc((size_t)SEQ * DHEAD * 4);

  // weight prep (bf16 + transpose to NxK)
  k_transpose<<<dim3(DMODEL / 32, DMODEL / 32, NL), 256, 0, stream>>>(Wq, wqt, DMODEL, DMODEL);
  k_transpose<<<dim3(DMODEL / 32, DMODEL / 32, NL), 256, 0, stream>>>(Wk, wkt, DMODEL, DMODEL);
  k_transpose<<<dim3(DMODEL / 32, DMODEL / 32, NL), 256, 0, stream>>>(Wv, wvt, DMODEL, DMODEL);
  k_transpose<<<dim3(DMODEL / 32, DMODEL / 32, NL), 256, 0, stream>>>(Wg, wgt, DMODEL, DMODEL);
  k_transpose<<<dim3(DMODEL / 32, DMODEL / 32, NL), 256, 0, stream>>>(Wo, wot, DMODEL, DMODEL);
  k_transpose<<<dim3(DFF / 32, DMODEL / 32, NL), 256, 0, stream>>>(W1, w1t, DMODEL, DFF);
  k_transpose<<<dim3(DMODEL / 32, DFF / 32, NL), 256, 0, stream>>>(W2, w2t, DFF, DMODEL);
  k_addpos<<<SEQ * DMODEL / 1024, 256, 0, stream>>>(x_in, pos, xb);
  k_sincos<<<SEQ * 32 / 256, 256, 0, stream>>>(sint, cost);

  for (int l = 0; l < NL; ++l) {
    k_ln<<<SEQ / 4, 256, 0, stream>>>(xb, ln1w + l * DMODEL, ln1b + l * DMODEL, ybf, 1e-5f);
    GArgs gq{};
    gq.M = SEQ; gq.N = DMODEL; gq.K = DMODEL;
    gq.b[0] = GB{ybf, wqt + l * DD, bq + l * DMODEL, qraw, 0};
    gq.b[1] = GB{ybf, wkt + l * DD, bk + l * DMODEL, kraw, 0};
    gq.b[2] = GB{ybf, wvt + l * DD, bv + l * DMODEL, vtb, 4};   // V stored transposed bf16
    gq.b[3] = GB{ybf, wgt + l * DD, bg + l * DMODEL, graw, 0};
    k_gemm<<<dim3(DMODEL / 64, SEQ / 64, 4), 256, 0, stream>>>(gq);
    k_rope<<<SEQ / 2, 256, 0, stream>>>(qraw, kraw, sint, cost, qb, kb);
    k_attn<<<dim3(32, NH, 2), 256, 0, stream>>>(qb, kb, vtb, ret0, ret1);
    k_retgate<<<SEQ * NH / 4, 256, 0, stream>>>(ret0, ret1, graw, grb);
    GArgs go{};
    go.M = SEQ; go.N = DMODEL; go.K = DMODEL;
    go.b[0] = GB{grb, wot + l * DD, bo + l * DMODEL, xb, 2};
    k_gemm<<<dim3(DMODEL / 64, SEQ / 64, 1), 256, 0, stream>>>(go);
    k_ln<<<SEQ / 4, 256, 0, stream>>>(xb, ln2w + l * DMODEL, ln2b + l * DMODEL, zbf, 1e-5f);
    GArgs g1{};
    g1.M = SEQ; g1.N = DFF; g1.K = DMODEL;
    g1.b[0] = GB{zbf, w1t + (size_t)l * DMODEL * DFF, b1 + l * DFF, hbf, 1};
    k_gemm<<<dim3(DFF / 64, SEQ / 64, 1), 256, 0, stream>>>(g1);
    GArgs g2{};
    g2.M = SEQ; g2.N = DMODEL; g2.K = DFF;
    g2.b[0] = GB{hbf, w2t + (size_t)l * DMODEL * DFF, b2 + l * DMODEL, xb, 2};
    k_gemm<<<dim3(DMODEL / 64, SEQ / 64, 1), 256, 0, stream>>>(g2);
  }
  k_final<<<SEQ / 4, 256, 0, stream>>>(xb, Wout, bout, out);
}